// Round 13
// baseline (217.415 us; speedup 1.0000x reference)
//
#include <hip/hip_runtime.h>
#include <float.h>

// VQ nearest-neighbor: 1-term bf16 MFMA (xh*eh) + best-4 margin certification +
// in-kernel exact-f32 candidate rescore + sliced full-scan fallback.
// dist = e2[k] - 2*dot.  Pass-1 error E<=0.5, key-quant 0.008; MARGIN=1.125:
//   v1-v0 >= M -> k0 exact.  v3-v0 < M -> full exact scan (rare, kernel 3).
//   else -> exact rescore of {k0..k3} in-block.
// R23 = R22's pair-staged schedule (4x16KB slots, 64 barriers, uniform
// vmcnt(0)+lgkmcnt(0)+barrier, dist-in-acc, stagger, setprio, EhS-aliased
// flags) with 1024-thread blocks: 16 waves in wr4 x wc4, wave = 16 rows x
// 32 cols.  Traffic model: per-CU LDS = waves x 2MB/wc reads + blocks x 2MB
// writes; R22 (wc2, 16 waves) = 20MB/CU; R23 (wc4, 32 waves) = 20MB/CU --
// SAME traffic, DOUBLE the resident waves (32/CU = capacity) to hide the
// port + rendezvous latency.  Needs VGPR <= 64 for 8 waves/SIMD: wave shape
// costs acc 8 + xh 32 + b4 16 ~ 56 (R22 measured 56 for a larger shape).
// wc4/j2/6-bit keys + 4-way merge = R17's correctness-verified code.
// Walls: VGPR 64-granule (R17); 2 independent blocks/CU mandatory (R18);
// 64KB/block LDS max (R22-verified packing).

#define HW 1024
#define CHW 262144
#define CODES_SIZE 8388608
#define NROWS 32768
#define KCB 4096
#define MARGIN 1.125f
#define DOFF 1024.0f

typedef short s16x8 __attribute__((ext_vector_type(8)));
typedef float f32x4 __attribute__((ext_vector_type(4)));

static __device__ __forceinline__ unsigned int bf16_rne(float f) {
    unsigned int u = __float_as_uint(f);
    return (u + 0x7FFFu + ((u >> 16) & 1u)) >> 16;
}
static __device__ __forceinline__ unsigned int f32_sortable(float d) {
    unsigned int s = __float_as_uint(d);
    return (s & 0x80000000u) ? ~s : (s | 0x80000000u);
}
static __device__ __forceinline__ void gload16(const uint4* g, uint4* lds) {
    __builtin_amdgcn_global_load_lds(
        (const __attribute__((address_space(1))) unsigned int*)g,
        (__attribute__((address_space(3))) unsigned int*)lds, 16, 0, 0);
}

// ---------- kernel 1: codebook -> eh bf16 plane + exact e2[k]; cntF init ----------
__global__ __launch_bounds__(256) void vq_prep_e_e2(const float4* __restrict__ cb4,
                                                    uint4* __restrict__ eh4,
                                                    float* __restrict__ e2,
                                                    unsigned int* __restrict__ cntF) {
    const int tid = threadIdx.x;
    const int gi = blockIdx.x * 256 + tid;           // 4096*32 granules
    if (gi == 0) *cntF = 0;
    const int k = gi >> 5, g = gi & 31;
    const float4 p = cb4[k * 64 + g * 2];
    const float4 q = cb4[k * 64 + g * 2 + 1];
    const float f[8] = {p.x, p.y, p.z, p.w, q.x, q.y, q.z, q.w};
    unsigned int h[8];
    float s = 0.0f;
    #pragma unroll
    for (int e = 0; e < 8; ++e) { h[e] = bf16_rne(f[e]); s = fmaf(f[e], f[e], s); }
    uint4 hi;
    hi.x = h[0] | (h[1] << 16); hi.y = h[2] | (h[3] << 16);
    hi.z = h[4] | (h[5] << 16); hi.w = h[6] | (h[7] << 16);
    eh4[gi] = hi;
    #pragma unroll
    for (int m = 1; m < 32; m <<= 1) s += __shfl_xor(s, m, 64);
    if ((tid & 31) == 0) e2[k] = s;
}

// ---------- kernel 2: approx MFMA GEMM + med3 best-4 + fused rescore ----------
// 1024 thr / 16 waves: wr = wid>>2 (rows wr*16..+15), wc = wid&3 (cols wc*32..+31).
// Block: 64 rows x full K scan; 64 phases of 2 chunks (32 KB staged/phase),
// tile order rotated by 8*(bid&3) (stagger across co-resident blocks).
__global__ __launch_bounds__(1024)
void vq_argmin_mfma(
        const float* __restrict__ x,
        const float* __restrict__ cb,
        const uint4* __restrict__ eh4,
        const float* __restrict__ e2g,
        float* __restrict__ out_idx,
        int* __restrict__ listF, unsigned int* __restrict__ cntF,
        unsigned long long* __restrict__ fbBest) {
    __shared__ uint4 EhS[4][1024];   // 2 halves x 2 chunks x 16 KB = 64 KB (all LDS)

    const int tid = threadIdx.x;
    const int lane = tid & 63, wid = tid >> 6;
    const int l15 = lane & 15, l4g = lane >> 4;
    const int wr = wid >> 2, wc = wid & 3;
    const int rowBase = blockIdx.x * 64;
    const int roff = (blockIdx.x & 3) << 3;   // stagger co-resident blocks

    // stage pair p (chunks 2p, 2p+1 = 32 KB) into half hf (slots hf*2, hf*2+1)
    auto stage = [&](int hf, int p) {
        #pragma unroll
        for (int q = 0; q < 2; ++q) {
            const int idx0 = (wid * 2 + q) * 64;      // 0..2047 spans 2 slots
            const int cip = idx0 >> 10;               // chunk-in-pair 0/1
            const int idxc = idx0 & 1023;             // index within slot
            const int chunk = 2 * p + cip;
            const int n = ((chunk >> 2) + roff) & 31, cc = chunk & 3;
            const int col_loc = (idxc >> 3) + (lane >> 3);
            const int g = lane & 7;
            const int srcg = g ^ (col_loc & 7);       // pre-swizzled source
            gload16(&eh4[(n * 128 + col_loc) * 32 + cc * 8 + srcg],
                    &EhS[hf * 2 + cip][idxc]);
        }
    };

    stage(0, 0);   // pair 0 in flight; e2+X phase below hides its latency

    // ---- e2 prefetch for first tile (drained by X-phase data-dep waits) ----
    float e2p[2];
    #pragma unroll
    for (int j = 0; j < 2; ++j)
        e2p[j] = e2g[(roff << 7) + wc * 32 + j * 16 + l15] + DOFF;

    // ---- X phase: xh = bf16(-2x) -> regs (stride-HW dword loads) ----
    s16x8 xh_r[4][2];   // [cc][ks] = 32 VGPR
    {
        const int row_g = rowBase + wr * 16 + l15;
        const int b = row_g >> 10, hw = row_g & 1023;
        const float* xb = x + b * CHW + hw;
        #pragma unroll
        for (int cc = 0; cc < 4; ++cc)
            #pragma unroll
            for (int ks = 0; ks < 2; ++ks) {
                const int c0 = cc * 64 + (ks * 4 + l4g) * 8;
                unsigned int h[8];
                #pragma unroll
                for (int e = 0; e < 8; ++e) h[e] = bf16_rne(-2.0f * xb[(c0 + e) * HW]);
                union { s16x8 v; unsigned int u[4]; } th;
                th.u[0] = h[0] | (h[1] << 16); th.u[1] = h[2] | (h[3] << 16);
                th.u[2] = h[4] | (h[5] << 16); th.u[3] = h[6] | (h[7] << 16);
                xh_r[cc][ks] = th.v;
            }
    }

    // sorted best-4 per slot (4 slots = r), ascending f32 (packed keys are
    // positive normal floats -> f32 order == u32 order; min/med3 insert = 4 ops)
    float b4[4][4];
    #pragma unroll
    for (int s = 0; s < 4; ++s)
        #pragma unroll
        for (int t = 0; t < 4; ++t) b4[s][t] = FLT_MAX;

    for (int n = 0; n < 32; ++n) {
        const int tn = (n + roff) & 31;         // rotated tile index
        f32x4 acc[2];                            // C-init at h0 from e2p

        #pragma unroll
        for (int h = 0; h < 2; ++h) {
            const int p = n * 2 + h;             // phase; pair p in half h (p&1==h)
            // Uniform phase entry (R21/R22-proven): drain ALL vmem (stage
            // issued last phase + e2 prefetch), service this wave's ds_reads
            // of the half about to be overwritten, rendezvous.
            asm volatile("s_waitcnt vmcnt(0)" ::: "memory");
            asm volatile("s_waitcnt lgkmcnt(0)" ::: "memory");
            asm volatile("s_barrier" ::: "memory");
            __builtin_amdgcn_sched_barrier(0);
            if (p + 1 < 64) stage(h ^ 1, p + 1);   // other half: readers passed barrier
            if (h == 0) {
                // C-init: acc = e2+DOFF (consumes e2p) ...
                #pragma unroll
                for (int j = 0; j < 2; ++j) {
                    f32x4 ci = {e2p[j], e2p[j], e2p[j], e2p[j]};
                    acc[j] = ci;
                }
                // ... then prefetch next tile's e2 (after stage in FIFO;
                // drained by next phase's vmcnt(0), consumed 2 phases later)
                if (n + 1 < 32) {
                    __builtin_amdgcn_sched_barrier(0);
                    const int tnn = (n + 1 + roff) & 31;
                    #pragma unroll
                    for (int j = 0; j < 2; ++j)
                        e2p[j] = e2g[(tnn << 7) + wc * 32 + j * 16 + l15] + DOFF;
                }
            }
            __builtin_amdgcn_s_setprio(1);
            #pragma unroll
            for (int cl = 0; cl < 2; ++cl) {       // 2 chunks this phase
                const int cc = 2 * h + cl;          // global c-chunk = xh index
                const int slot = h * 2 + cl;
                #pragma unroll
                for (int ks = 0; ks < 2; ++ks) {
                    const int cg = ks * 4 + l4g;
                    #pragma unroll
                    for (int j = 0; j < 2; ++j) {
                        const int col = wc * 32 + j * 16 + l15;
                        uint4 th = EhS[slot][col * 8 + (cg ^ (col & 7))];
                        s16x8 bh = *(s16x8*)&th;
                        acc[j] = __builtin_amdgcn_mfma_f32_16x16x32_bf16(
                            xh_r[cc][ks], bh, acc[j], 0, 0, 0);
                    }
                }
            }
            __builtin_amdgcn_s_setprio(0);
        }

        // epilogue: acc IS the offset distance; pack key + min/med3 insert
        // (~5 VALU/dist).  6-bit local key tn*2+j, quant <=0.008 << MARGIN.
        #pragma unroll
        for (int j = 0; j < 2; ++j) {
            const unsigned int kloc = (unsigned)(tn * 2 + j);
            #pragma unroll
            for (int r = 0; r < 4; ++r) {
                const float p = __uint_as_float(
                    (__float_as_uint(acc[j][r]) & ~63u) | kloc);
                const float o0 = b4[r][0], o1 = b4[r][1], o2 = b4[r][2];
                b4[r][0] = fminf(o0, p);
                b4[r][1] = __builtin_amdgcn_fmed3f(o0, b4[r][1], p);
                b4[r][2] = __builtin_amdgcn_fmed3f(o1, b4[r][2], p);
                b4[r][3] = __builtin_amdgcn_fmed3f(o2, b4[r][3], p);
            }
        }
    }

    // ---- decode 6-bit local keys to full k (R17-verified decode) ----
    float dv[4][4]; int dk[4][4];
    #pragma unroll
    for (int s = 0; s < 4; ++s)
        #pragma unroll
        for (int t = 0; t < 4; ++t) {
            const unsigned int u = __float_as_uint(b4[s][t]);
            const int kl = (int)(u & 63u);
            dv[s][t] = __uint_as_float(u & ~63u);
            dk[s][t] = ((kl >> 1) << 7) + wc * 32 + ((kl & 1) << 4) + l15;
        }

    // merge two sorted-4 (ascending f32) -> sorted top-4
    auto merge4 = [](float av[4], int ak[4],
                     const float bv[4], const int bk[4]) {
        float pv[4], qv[4]; int pk[4], qk[4];
        #pragma unroll
        for (int t = 0; t < 4; ++t) {
            const bool bl = bv[t] < av[t];
            pv[t] = bl ? bv[t] : av[t]; pk[t] = bl ? bk[t] : ak[t];
            qv[t] = bl ? av[t] : bv[t]; qk[t] = bl ? ak[t] : bk[t];
        }
        const bool c1 = qv[0] < pv[1];
        const float r1v = c1 ? qv[0] : pv[1]; const int r1k = c1 ? qk[0] : pk[1];
        const float x1v = c1 ? pv[1] : qv[0]; const int x1k = c1 ? pk[1] : qk[0];
        const bool c2 = pv[2] < x1v;
        const float r2v = c2 ? pv[2] : x1v;   const int r2k = c2 ? pk[2] : x1k;
        const bool c3 = qv[0] < pv[2];
        const float x2v = c3 ? pv[2] : qv[0]; const int x2k = c3 ? pk[2] : qk[0];
        const bool c4 = x2v < qv[1];
        const float t4v = c4 ? x2v : qv[1];   const int t4k = c4 ? x2k : qk[1];
        const bool c5 = pv[3] < t4v;
        const float r3v = c5 ? pv[3] : t4v;   const int r3k = c5 ? pk[3] : t4k;
        av[0] = pv[0]; ak[0] = pk[0];
        av[1] = r1v;   ak[1] = r1k;
        av[2] = r2v;   ak[2] = r2k;
        av[3] = r3v;   ak[3] = r3k;
    };

    // ---- cross-lane merge (16-lane k-groups share rows) ----
    #pragma unroll
    for (int m = 1; m < 16; m <<= 1) {
        #pragma unroll
        for (int s = 0; s < 4; ++s) {
            float bv[4]; int bk[4];
            #pragma unroll
            for (int t = 0; t < 4; ++t) {
                bv[t] = __shfl_xor(dv[s][t], m, 16);
                bk[t] = __shfl_xor(dk[s][t], m, 16);
            }
            merge4(dv[s], dk[s], bv, bk);
        }
    }

    // ---- cross-wave (wc=1..3 -> wc=0) merge + flags, aliased into dead EhS ----
    unsigned int* lbase = (unsigned int*)EhS;
    unsigned int* mbuf = lbase;                       // 3 x 64 rows x 8 u32
    int* flagRow = (int*)(lbase + 2048);              // 64
    int (*flagK)[4] = (int(*)[4])(lbase + 2304);      // 64 x 4
    unsigned int* pnflag = lbase + 4000;
    __syncthreads();    // ALL K-loop LDS reads complete before alias writes
    if (tid == 0) *pnflag = 0;
    __syncthreads();
    if (wc > 0 && l15 == 0) {
        #pragma unroll
        for (int r = 0; r < 4; ++r) {
            const int rl = wr * 16 + l4g * 4 + r;
            const int base = ((wc - 1) * 64 + rl) * 8;
            #pragma unroll
            for (int t = 0; t < 4; ++t) {
                mbuf[base + t]     = __float_as_uint(dv[r][t]);
                mbuf[base + 4 + t] = (unsigned int)dk[r][t];
            }
        }
    }
    __syncthreads();
    if (wc == 0 && l15 == 0) {
        #pragma unroll
        for (int r = 0; r < 4; ++r) {
            const int rl = wr * 16 + l4g * 4 + r;
            #pragma unroll
            for (int w = 0; w < 3; ++w) {
                const int base = (w * 64 + rl) * 8;
                float bv[4]; int bk[4];
                #pragma unroll
                for (int t = 0; t < 4; ++t) {
                    bv[t] = __uint_as_float(mbuf[base + t]);
                    bk[t] = (int)mbuf[base + 4 + t];
                }
                merge4(dv[r], dk[r], bv, bk);
            }
            const int rg = rowBase + rl;
            const float v0 = dv[r][0];
            const float v1 = dv[r][1];
            const float v3 = dv[r][3];
            if (v3 - v0 < MARGIN) {                      // rare: full exact scan
                out_idx[rg] = -1.0f;                     // sentinel for gather
                fbBest[rg] = ~0ull;
                const unsigned int pos = atomicAdd(cntF, 1u);
                listF[pos] = rg;
            } else {
                out_idx[rg] = (float)dk[r][0];           // provisional/final
                if (v1 - v0 < MARGIN) {                  // in-block exact rescore
                    const unsigned int pos = atomicAdd(pnflag, 1u);
                    flagRow[pos] = rl;
                    flagK[pos][0] = dk[r][0]; flagK[pos][1] = dk[r][1];
                    flagK[pos][2] = dk[r][2]; flagK[pos][3] = dk[r][3];
                }
            }
        }
    }
    __syncthreads();

    // ---- fused exact f32 rescore: wave per flagged row, x rows cache-warm ----
    const unsigned int nf = *pnflag;
    for (unsigned int e = wid; e < nf; e += 16) {
        const int rl = flagRow[e];
        const int rg = rowBase + rl;
        const int b = rg >> 10, hw = rg & 1023;
        const int kc = flagK[e][lane >> 4];
        const float* xb = x + b * CHW + hw;
        const float* eb = cb + kc * 256;
        float dot = 0.0f;
        #pragma unroll 4
        for (int t = lane & 15; t < 256; t += 16)
            dot = fmaf(xb[t * HW], eb[t], dot);
        #pragma unroll
        for (int m = 1; m < 16; m <<= 1) dot += __shfl_xor(dot, m, 16);
        const float d = fmaf(-2.0f, dot, e2g[kc]);
        float bd = d; int bk = kc;
        #pragma unroll
        for (int c = 1; c < 4; ++c) {
            const float od = __shfl(d, c * 16, 64);
            const int   ok = __shfl(kc, c * 16, 64);
            if (od < bd || (od == bd && ok < bk)) { bd = od; bk = ok; }
        }
        if (lane == 0) out_idx[rg] = (float)bk;
    }
}

// ---------- kernel 3: sliced exact f32 full scan (8 blocks per flagged row) ----------
__global__ __launch_bounds__(256) void vq_fallback(
        const float* __restrict__ x, const float4* __restrict__ cb4,
        const float* __restrict__ e2g, const int* __restrict__ listF,
        const unsigned int* __restrict__ cntF,
        unsigned long long* __restrict__ fbBest) {
    __shared__ float xrow[256];
    const int li = blockIdx.x >> 3, sl = blockIdx.x & 7;
    if (li >= (int)*cntF) return;
    const int row = listF[li];
    const int b = row >> 10, hw = row & 1023;
    const int tid = threadIdx.x;
    xrow[tid] = x[b * CHW + tid * HW + hw];
    __syncthreads();
    float bestv = FLT_MAX; int bestk = 0;
    #pragma unroll
    for (int kk = 0; kk < 2; ++kk) {
        const int k = sl * 512 + kk * 256 + tid;
        float dot = 0.0f;
        #pragma unroll 8
        for (int c4 = 0; c4 < 64; ++c4) {
            const float4 e = cb4[k * 64 + c4];
            dot = fmaf(xrow[c4 * 4 + 0], e.x, dot);
            dot = fmaf(xrow[c4 * 4 + 1], e.y, dot);
            dot = fmaf(xrow[c4 * 4 + 2], e.z, dot);
            dot = fmaf(xrow[c4 * 4 + 3], e.w, dot);
        }
        const float d = fmaf(-2.0f, dot, e2g[k]);
        if (d < bestv) { bestv = d; bestk = k; }   // k ascending per thread
    }
    unsigned long long p = ((unsigned long long)f32_sortable(bestv) << 32)
                         | (unsigned int)bestk;    // tie -> smaller k wins
    #pragma unroll
    for (int m = 1; m < 64; m <<= 1) {
        const unsigned long long op = __shfl_xor(p, m, 64);
        p = op < p ? op : p;
    }
    if ((tid & 63) == 0) atomicMin(&fbBest[row], p);
}

// ---------- kernel 4: gather codes + resolve fallback sentinel ----------
__global__ __launch_bounds__(256) void vq_gather(const float4* __restrict__ cb4,
                                                 float* __restrict__ out_idx,
                                                 const unsigned long long* __restrict__ fbBest,
                                                 float* __restrict__ out) {
    const int gid = blockIdx.x * 256 + threadIdx.x;
    const int w = gid & 31, h = (gid >> 5) & 31, c4 = (gid >> 10) & 63, b = gid >> 16;
    const int row = b * HW + h * 32 + w;
    int k = (int)out_idx[row];
    if (k < 0) k = (int)(unsigned int)(fbBest[row] & 0xFFFFFFFFull);
    if (c4 == 0) out_idx[row] = (float)k;   // benign race: all writers write same k
    const float4 v = cb4[k * 64 + c4];
    const int ob = b * CHW + (c4 * 4) * HW + h * 32 + w;
    out[ob] = v.x; out[ob + HW] = v.y; out[ob + 2 * HW] = v.z; out[ob + 3 * HW] = v.w;
}

extern "C" void kernel_launch(void* const* d_in, const int* in_sizes, int n_in,
                              void* d_out, int out_size, void* d_ws, size_t ws_size,
                              hipStream_t stream) {
    const float* x = (const float*)d_in[0];
    const float* cb = (const float*)d_in[1];
    float* out = (float*)d_out;
    float* out_idx = out + CODES_SIZE;

    char* wsb = (char*)d_ws;
    float* e2 = (float*)wsb;                                        // 16 KB
    unsigned int* cntF = (unsigned int*)(wsb + (16 << 10));         // 4 B
    int* listF = (int*)(wsb + (32 << 10));                          // 128 KB
    unsigned long long* fbBest = (unsigned long long*)(wsb + (256 << 10)); // 256 KB
    uint4* eh4 = (uint4*)(wsb + (512 << 10));                       // 2.10 MB

    vq_prep_e_e2<<<512, 256, 0, stream>>>((const float4*)cb, eh4, e2, cntF);
    vq_argmin_mfma<<<512, 1024, 0, stream>>>(x, cb, eh4, e2, out_idx,
                                             listF, cntF, fbBest);
    vq_fallback<<<2048, 256, 0, stream>>>(x, (const float4*)cb, e2, listF, cntF, fbBest);
    vq_gather<<<8192, 256, 0, stream>>>((const float4*)cb, out_idx, fbBest, out);
}

// Round 14
// 155.207 us; speedup vs baseline: 1.4008x; 1.4008x over previous
//
#include <hip/hip_runtime.h>
#include <float.h>

// VQ nearest-neighbor: 1-term bf16 MFMA (xh*eh) + best-4 margin certification +
// in-kernel exact-f32 candidate rescore + sliced full-scan fallback.
// dist = e2[k] - 2*dot.  Pass-1 error E<=0.5, key-quant 0.031; MARGIN=1.125:
//   v1-v0 >= M -> k0 exact.  v3-v0 < M -> full exact scan (rare, kernel 3).
//   else -> exact rescore of {k0..k3} in-block.
// R24 = R22 (best verified: 126.6us argmin / 158.7 total; pair-staged 4x16KB
// slots, 64 barriers, uniform vmcnt(0)+lgkmcnt(0)+barrier, dist-in-acc,
// stagger, setprio, 2 independent 8-wave blocks/CU) + GATHER FUSION:
// argmin blocks write the 64x256 code tile for their own rows (kRow[64] LDS:
// certify -> k or -1; rescore updates; cooperative 64KB coalesced write,
// codebook L2-warm).  Old grid-8192 vq_gather (~10-14us + gap) replaced by a
// slim grid-stride vq_gather_fb that only resolves fallback-sentinel rows.
// K-loop byte-identical to R22.
// Walls (measured): VGPR 64-granule (R17); 2 independent sub-max blocks/CU
// mandatory -- 1024-thr blocks do NOT co-schedule (R18, R23); 64KB/block LDS
// max for 2-block packing (R22); LDS-port ~98us floor inside argmin.

#define HW 1024
#define CHW 262144
#define CODES_SIZE 8388608
#define NROWS 32768
#define KCB 4096
#define MARGIN 1.125f
#define DOFF 1024.0f

typedef short s16x8 __attribute__((ext_vector_type(8)));
typedef float f32x4 __attribute__((ext_vector_type(4)));

static __device__ __forceinline__ unsigned int bf16_rne(float f) {
    unsigned int u = __float_as_uint(f);
    return (u + 0x7FFFu + ((u >> 16) & 1u)) >> 16;
}
static __device__ __forceinline__ unsigned int f32_sortable(float d) {
    unsigned int s = __float_as_uint(d);
    return (s & 0x80000000u) ? ~s : (s | 0x80000000u);
}
static __device__ __forceinline__ void gload16(const uint4* g, uint4* lds) {
    __builtin_amdgcn_global_load_lds(
        (const __attribute__((address_space(1))) unsigned int*)g,
        (__attribute__((address_space(3))) unsigned int*)lds, 16, 0, 0);
}

// ---------- kernel 1: codebook -> eh bf16 plane + exact e2[k]; cntF init ----------
__global__ __launch_bounds__(256) void vq_prep_e_e2(const float4* __restrict__ cb4,
                                                    uint4* __restrict__ eh4,
                                                    float* __restrict__ e2,
                                                    unsigned int* __restrict__ cntF) {
    const int tid = threadIdx.x;
    const int gi = blockIdx.x * 256 + tid;           // 4096*32 granules
    if (gi == 0) *cntF = 0;
    const int k = gi >> 5, g = gi & 31;
    const float4 p = cb4[k * 64 + g * 2];
    const float4 q = cb4[k * 64 + g * 2 + 1];
    const float f[8] = {p.x, p.y, p.z, p.w, q.x, q.y, q.z, q.w};
    unsigned int h[8];
    float s = 0.0f;
    #pragma unroll
    for (int e = 0; e < 8; ++e) { h[e] = bf16_rne(f[e]); s = fmaf(f[e], f[e], s); }
    uint4 hi;
    hi.x = h[0] | (h[1] << 16); hi.y = h[2] | (h[3] << 16);
    hi.z = h[4] | (h[5] << 16); hi.w = h[6] | (h[7] << 16);
    eh4[gi] = hi;
    #pragma unroll
    for (int m = 1; m < 32; m <<= 1) s += __shfl_xor(s, m, 64);
    if ((tid & 31) == 0) e2[k] = s;
}

// ---------- kernel 2: approx MFMA GEMM + med3 best-4 + rescore + code write ----------
// 512 thr / 8 waves: wr = wid>>1 (rows wr*16..+15), wc = wid&1 (cols wc*64..+63).
// Block: 64 rows x full K scan; 64 phases of 2 chunks (32 KB staged/phase),
// tile order rotated by 8*(bid&3) (stagger across co-resident blocks).
__global__ __launch_bounds__(512)
void vq_argmin_mfma(
        const float* __restrict__ x,
        const float* __restrict__ cb,
        const uint4* __restrict__ eh4,
        const float* __restrict__ e2g,
        float* __restrict__ out_idx,
        int* __restrict__ listF, unsigned int* __restrict__ cntF,
        unsigned long long* __restrict__ fbBest,
        float* __restrict__ out) {
    __shared__ uint4 EhS[4][1024];   // 2 halves x 2 chunks x 16 KB = 64 KB (all LDS)

    const int tid = threadIdx.x;
    const int lane = tid & 63, wid = tid >> 6;
    const int l15 = lane & 15, l4g = lane >> 4;
    const int wr = wid >> 1, wc = wid & 1;
    const int rowBase = blockIdx.x * 64;
    const int roff = (blockIdx.x & 3) << 3;   // stagger co-resident blocks

    // stage pair p (chunks 2p, 2p+1 = 32 KB) into half hf (slots hf*2, hf*2+1)
    auto stage = [&](int hf, int p) {
        #pragma unroll
        for (int q = 0; q < 4; ++q) {
            const int idx0 = (wid * 4 + q) * 64;      // 0..2047 spans 2 slots
            const int cip = idx0 >> 10;               // chunk-in-pair 0/1
            const int idxc = idx0 & 1023;             // index within slot
            const int chunk = 2 * p + cip;
            const int n = ((chunk >> 2) + roff) & 31, cc = chunk & 3;
            const int col_loc = (idxc >> 3) + (lane >> 3);
            const int g = lane & 7;
            const int srcg = g ^ (col_loc & 7);       // pre-swizzled source
            gload16(&eh4[(n * 128 + col_loc) * 32 + cc * 8 + srcg],
                    &EhS[hf * 2 + cip][idxc]);
        }
    };

    stage(0, 0);   // pair 0 in flight; e2+X phase below hides its latency

    // ---- e2 prefetch for first tile (drained by X-phase data-dep waits) ----
    float e2p[4];
    #pragma unroll
    for (int j = 0; j < 4; ++j)
        e2p[j] = e2g[(roff << 7) + wc * 64 + j * 16 + l15] + DOFF;

    // ---- X phase: xh = bf16(-2x) -> regs (stride-HW dword loads) ----
    s16x8 xh_r[4][2];   // [cc][ks] = 32 VGPR
    {
        const int row_g = rowBase + wr * 16 + l15;
        const int b = row_g >> 10, hw = row_g & 1023;
        const float* xb = x + b * CHW + hw;
        #pragma unroll
        for (int cc = 0; cc < 4; ++cc)
            #pragma unroll
            for (int ks = 0; ks < 2; ++ks) {
                const int c0 = cc * 64 + (ks * 4 + l4g) * 8;
                unsigned int h[8];
                #pragma unroll
                for (int e = 0; e < 8; ++e) h[e] = bf16_rne(-2.0f * xb[(c0 + e) * HW]);
                union { s16x8 v; unsigned int u[4]; } th;
                th.u[0] = h[0] | (h[1] << 16); th.u[1] = h[2] | (h[3] << 16);
                th.u[2] = h[4] | (h[5] << 16); th.u[3] = h[6] | (h[7] << 16);
                xh_r[cc][ks] = th.v;
            }
    }

    // sorted best-4 per slot (4 slots = r), ascending f32 (packed keys are
    // positive normal floats -> f32 order == u32 order; min/med3 insert = 4 ops)
    float b4[4][4];
    #pragma unroll
    for (int s = 0; s < 4; ++s)
        #pragma unroll
        for (int t = 0; t < 4; ++t) b4[s][t] = FLT_MAX;

    for (int n = 0; n < 32; ++n) {
        const int tn = (n + roff) & 31;         // rotated tile index
        f32x4 acc[4];                            // C-init at h0 from e2p

        #pragma unroll
        for (int h = 0; h < 2; ++h) {
            const int p = n * 2 + h;             // phase; pair p in half h (p&1==h)
            // Uniform phase entry (R21/R22-proven): drain ALL vmem (stage
            // issued last phase + e2 prefetch), service this wave's ds_reads
            // of the half about to be overwritten, rendezvous.
            asm volatile("s_waitcnt vmcnt(0)" ::: "memory");
            asm volatile("s_waitcnt lgkmcnt(0)" ::: "memory");
            asm volatile("s_barrier" ::: "memory");
            __builtin_amdgcn_sched_barrier(0);
            if (p + 1 < 64) stage(h ^ 1, p + 1);   // other half: readers passed barrier
            if (h == 0) {
                // C-init: acc = e2+DOFF (consumes e2p) ...
                #pragma unroll
                for (int j = 0; j < 4; ++j) {
                    f32x4 ci = {e2p[j], e2p[j], e2p[j], e2p[j]};
                    acc[j] = ci;
                }
                // ... then prefetch next tile's e2 (after stage in FIFO;
                // drained by next phase's vmcnt(0), consumed 2 phases later)
                if (n + 1 < 32) {
                    __builtin_amdgcn_sched_barrier(0);
                    const int tnn = (n + 1 + roff) & 31;
                    #pragma unroll
                    for (int j = 0; j < 4; ++j)
                        e2p[j] = e2g[(tnn << 7) + wc * 64 + j * 16 + l15] + DOFF;
                }
            }
            __builtin_amdgcn_s_setprio(1);
            #pragma unroll
            for (int cl = 0; cl < 2; ++cl) {       // 2 chunks this phase
                const int cc = 2 * h + cl;          // global c-chunk = xh index
                const int slot = h * 2 + cl;
                #pragma unroll
                for (int ks = 0; ks < 2; ++ks) {
                    const int cg = ks * 4 + l4g;
                    #pragma unroll
                    for (int j = 0; j < 4; ++j) {
                        const int col = wc * 64 + j * 16 + l15;
                        uint4 th = EhS[slot][col * 8 + (cg ^ (col & 7))];
                        s16x8 bh = *(s16x8*)&th;
                        acc[j] = __builtin_amdgcn_mfma_f32_16x16x32_bf16(
                            xh_r[cc][ks], bh, acc[j], 0, 0, 0);
                    }
                }
            }
            __builtin_amdgcn_s_setprio(0);
        }

        // epilogue: acc IS the offset distance; pack key + min/med3 insert
        // (~5 VALU/dist).  7-bit local key tn*4+j, quant <=0.031 << MARGIN.
        #pragma unroll
        for (int j = 0; j < 4; ++j) {
            const unsigned int kloc = (unsigned)(tn * 4 + j);
            #pragma unroll
            for (int r = 0; r < 4; ++r) {
                const float p = __uint_as_float(
                    (__float_as_uint(acc[j][r]) & ~127u) | kloc);
                const float o0 = b4[r][0], o1 = b4[r][1], o2 = b4[r][2];
                b4[r][0] = fminf(o0, p);
                b4[r][1] = __builtin_amdgcn_fmed3f(o0, b4[r][1], p);
                b4[r][2] = __builtin_amdgcn_fmed3f(o1, b4[r][2], p);
                b4[r][3] = __builtin_amdgcn_fmed3f(o2, b4[r][3], p);
            }
        }
    }

    // ---- decode 7-bit local keys to full k; (value, key) pairs from here ----
    float dv[4][4]; int dk[4][4];
    #pragma unroll
    for (int s = 0; s < 4; ++s)
        #pragma unroll
        for (int t = 0; t < 4; ++t) {
            const unsigned int u = __float_as_uint(b4[s][t]);
            const int kl = (int)(u & 127u);
            dv[s][t] = __uint_as_float(u & ~127u);
            dk[s][t] = ((kl >> 2) << 7) + wc * 64 + ((kl & 3) << 4) + l15;
        }

    // merge two sorted-4 (ascending f32) -> sorted top-4
    auto merge4 = [](float av[4], int ak[4],
                     const float bv[4], const int bk[4]) {
        float pv[4], qv[4]; int pk[4], qk[4];
        #pragma unroll
        for (int t = 0; t < 4; ++t) {
            const bool bl = bv[t] < av[t];
            pv[t] = bl ? bv[t] : av[t]; pk[t] = bl ? bk[t] : ak[t];
            qv[t] = bl ? av[t] : bv[t]; qk[t] = bl ? ak[t] : bk[t];
        }
        const bool c1 = qv[0] < pv[1];
        const float r1v = c1 ? qv[0] : pv[1]; const int r1k = c1 ? qk[0] : pk[1];
        const float x1v = c1 ? pv[1] : qv[0]; const int x1k = c1 ? pk[1] : qk[0];
        const bool c2 = pv[2] < x1v;
        const float r2v = c2 ? pv[2] : x1v;   const int r2k = c2 ? pk[2] : x1k;
        const bool c3 = qv[0] < pv[2];
        const float x2v = c3 ? pv[2] : qv[0]; const int x2k = c3 ? pk[2] : qk[0];
        const bool c4 = x2v < qv[1];
        const float t4v = c4 ? x2v : qv[1];   const int t4k = c4 ? x2k : qk[1];
        const bool c5 = pv[3] < t4v;
        const float r3v = c5 ? pv[3] : t4v;   const int r3k = c5 ? pk[3] : t4k;
        av[0] = pv[0]; ak[0] = pk[0];
        av[1] = r1v;   ak[1] = r1k;
        av[2] = r2v;   ak[2] = r2k;
        av[3] = r3v;   ak[3] = r3k;
    };

    // ---- cross-lane merge (16-lane k-groups share rows) ----
    #pragma unroll
    for (int m = 1; m < 16; m <<= 1) {
        #pragma unroll
        for (int s = 0; s < 4; ++s) {
            float bv[4]; int bk[4];
            #pragma unroll
            for (int t = 0; t < 4; ++t) {
                bv[t] = __shfl_xor(dv[s][t], m, 16);
                bk[t] = __shfl_xor(dk[s][t], m, 16);
            }
            merge4(dv[s], dk[s], bv, bk);
        }
    }

    // ---- cross-wave (wc) merge + flags + kRow, aliased into dead EhS ----
    unsigned int* lbase = (unsigned int*)EhS;
    unsigned int* mbuf = lbase;                       // 64 rows x 8 u32
    int* flagRow = (int*)(lbase + 1024);              // 64
    int (*flagK)[4] = (int(*)[4])(lbase + 2048);      // 64 x 4
    unsigned int* pnflag = lbase + 4000;
    int* kRow = (int*)(lbase + 4096);                 // 64: final k or -1
    __syncthreads();    // ALL K-loop LDS reads complete before alias writes
    if (tid == 0) *pnflag = 0;
    __syncthreads();
    if (wc == 1 && l15 == 0) {
        #pragma unroll
        for (int r = 0; r < 4; ++r) {
            const int rl = wr * 16 + l4g * 4 + r;
            #pragma unroll
            for (int t = 0; t < 4; ++t) {
                mbuf[rl * 8 + t]     = __float_as_uint(dv[r][t]);
                mbuf[rl * 8 + 4 + t] = (unsigned int)dk[r][t];
            }
        }
    }
    __syncthreads();
    if (wc == 0 && l15 == 0) {
        #pragma unroll
        for (int r = 0; r < 4; ++r) {
            const int rl = wr * 16 + l4g * 4 + r;
            float bv[4]; int bk[4];
            #pragma unroll
            for (int t = 0; t < 4; ++t) {
                bv[t] = __uint_as_float(mbuf[rl * 8 + t]);
                bk[t] = (int)mbuf[rl * 8 + 4 + t];
            }
            merge4(dv[r], dk[r], bv, bk);
            const int rg = rowBase + rl;
            const float v0 = dv[r][0];
            const float v1 = dv[r][1];
            const float v3 = dv[r][3];
            if (v3 - v0 < MARGIN) {                      // rare: full exact scan
                out_idx[rg] = -1.0f;                     // sentinel for gather_fb
                kRow[rl] = -1;
                fbBest[rg] = ~0ull;
                const unsigned int pos = atomicAdd(cntF, 1u);
                listF[pos] = rg;
            } else {
                out_idx[rg] = (float)dk[r][0];           // provisional/final
                kRow[rl] = dk[r][0];
                if (v1 - v0 < MARGIN) {                  // in-block exact rescore
                    const unsigned int pos = atomicAdd(pnflag, 1u);
                    flagRow[pos] = rl;
                    flagK[pos][0] = dk[r][0]; flagK[pos][1] = dk[r][1];
                    flagK[pos][2] = dk[r][2]; flagK[pos][3] = dk[r][3];
                }
            }
        }
    }
    __syncthreads();

    // ---- fused exact f32 rescore: wave per flagged row, x rows cache-warm ----
    const unsigned int nf = *pnflag;
    for (unsigned int e = wid; e < nf; e += 8) {
        const int rl = flagRow[e];
        const int rg = rowBase + rl;
        const int b = rg >> 10, hw = rg & 1023;
        const int kc = flagK[e][lane >> 4];
        const float* xb = x + b * CHW + hw;
        const float* eb = cb + kc * 256;
        float dot = 0.0f;
        #pragma unroll 4
        for (int t = lane & 15; t < 256; t += 16)
            dot = fmaf(xb[t * HW], eb[t], dot);
        #pragma unroll
        for (int m = 1; m < 16; m <<= 1) dot += __shfl_xor(dot, m, 16);
        const float d = fmaf(-2.0f, dot, e2g[kc]);
        float bd = d; int bk = kc;
        #pragma unroll
        for (int c = 1; c < 4; ++c) {
            const float od = __shfl(d, c * 16, 64);
            const int   ok = __shfl(kc, c * 16, 64);
            if (od < bd || (od == bd && ok < bk)) { bd = od; bk = ok; }
        }
        if (lane == 0) { out_idx[rg] = (float)bk; kRow[rl] = bk; }
    }
    __syncthreads();

    // ---- fused code write: 64 rows x 256 ch (64 KB, 256B-coalesced).
    // All 64 rows share b (64 | 1024); codebook is L2-warm.  Sentinel rows
    // (k<0, rare) are written by vq_gather_fb after the full-scan fallback.
    {
        const int b0 = rowBase >> 10, hw0 = rowBase & 1023;
        const float4* cbb = (const float4*)cb;
        #pragma unroll
        for (int it = 0; it < 8; ++it) {
            const int item = it * 512 + tid;         // 64 rows x 64 c4-groups
            const int w6 = item & 63, c4 = item >> 6;
            const int k = kRow[w6];
            if (k >= 0) {
                const float4 v = cbb[k * 64 + c4];
                const int ob = b0 * CHW + (c4 * 4) * HW + hw0 + w6;
                out[ob] = v.x; out[ob + HW] = v.y;
                out[ob + 2 * HW] = v.z; out[ob + 3 * HW] = v.w;
            }
        }
    }
}

// ---------- kernel 3: sliced exact f32 full scan (8 blocks per flagged row) ----------
__global__ __launch_bounds__(256) void vq_fallback(
        const float* __restrict__ x, const float4* __restrict__ cb4,
        const float* __restrict__ e2g, const int* __restrict__ listF,
        const unsigned int* __restrict__ cntF,
        unsigned long long* __restrict__ fbBest) {
    __shared__ float xrow[256];
    const int li = blockIdx.x >> 3, sl = blockIdx.x & 7;
    if (li >= (int)*cntF) return;
    const int row = listF[li];
    const int b = row >> 10, hw = row & 1023;
    const int tid = threadIdx.x;
    xrow[tid] = x[b * CHW + tid * HW + hw];
    __syncthreads();
    float bestv = FLT_MAX; int bestk = 0;
    #pragma unroll
    for (int kk = 0; kk < 2; ++kk) {
        const int k = sl * 512 + kk * 256 + tid;
        float dot = 0.0f;
        #pragma unroll 8
        for (int c4 = 0; c4 < 64; ++c4) {
            const float4 e = cb4[k * 64 + c4];
            dot = fmaf(xrow[c4 * 4 + 0], e.x, dot);
            dot = fmaf(xrow[c4 * 4 + 1], e.y, dot);
            dot = fmaf(xrow[c4 * 4 + 2], e.z, dot);
            dot = fmaf(xrow[c4 * 4 + 3], e.w, dot);
        }
        const float d = fmaf(-2.0f, dot, e2g[k]);
        if (d < bestv) { bestv = d; bestk = k; }   // k ascending per thread
    }
    unsigned long long p = ((unsigned long long)f32_sortable(bestv) << 32)
                         | (unsigned int)bestk;    // tie -> smaller k wins
    #pragma unroll
    for (int m = 1; m < 64; m <<= 1) {
        const unsigned long long op = __shfl_xor(p, m, 64);
        p = op < p ? op : p;
    }
    if ((tid & 63) == 0) atomicMin(&fbBest[row], p);
}

// ---------- kernel 4 (slim): resolve fallback rows only, grid-stride ----------
__global__ __launch_bounds__(256) void vq_gather_fb(
        const float4* __restrict__ cb4, const int* __restrict__ listF,
        const unsigned int* __restrict__ cntF,
        const unsigned long long* __restrict__ fbBest,
        float* __restrict__ out_idx, float* __restrict__ out) {
    const unsigned int nf = *cntF;
    for (unsigned int item = blockIdx.x * 256 + threadIdx.x; item < nf * 64;
         item += gridDim.x * 256) {
        const int li = (int)(item >> 6), c4 = (int)(item & 63);
        const int row = listF[li];
        const int k = (int)(unsigned int)(fbBest[row] & 0xFFFFFFFFull);
        if (c4 == 0) out_idx[row] = (float)k;
        const int b = row >> 10, hw = row & 1023;
        const float4 v = cb4[k * 64 + c4];
        const int ob = b * CHW + (c4 * 4) * HW + hw;
        out[ob] = v.x; out[ob + HW] = v.y;
        out[ob + 2 * HW] = v.z; out[ob + 3 * HW] = v.w;
    }
}

extern "C" void kernel_launch(void* const* d_in, const int* in_sizes, int n_in,
                              void* d_out, int out_size, void* d_ws, size_t ws_size,
                              hipStream_t stream) {
    const float* x = (const float*)d_in[0];
    const float* cb = (const float*)d_in[1];
    float* out = (float*)d_out;
    float* out_idx = out + CODES_SIZE;

    char* wsb = (char*)d_ws;
    float* e2 = (float*)wsb;                                        // 16 KB
    unsigned int* cntF = (unsigned int*)(wsb + (16 << 10));         // 4 B
    int* listF = (int*)(wsb + (32 << 10));                          // 128 KB
    unsigned long long* fbBest = (unsigned long long*)(wsb + (256 << 10)); // 256 KB
    uint4* eh4 = (uint4*)(wsb + (512 << 10));                       // 2.10 MB

    vq_prep_e_e2<<<512, 256, 0, stream>>>((const float4*)cb, eh4, e2, cntF);
    vq_argmin_mfma<<<512, 512, 0, stream>>>(x, cb, eh4, e2, out_idx,
                                            listF, cntF, fbBest, out);
    vq_fallback<<<2048, 256, 0, stream>>>(x, (const float4*)cb, e2, listF, cntF, fbBest);
    vq_gather_fb<<<256, 256, 0, stream>>>((const float4*)cb, listF, cntF, fbBest,
                                          out_idx, out);
}